// Round 14
// baseline (365.617 us; speedup 1.0000x reference)
//
#include <hip/hip_runtime.h>

// Problem constants (fixed by the reference)
#define NHEADS 8
#define NKVH   2
#define HD     256
#define SEQ    4096
#define HID    2048
#define QKVN   3072   // (NH + 2*NKV) * D
#define SCAL   (1.0f/256.0f)
#define NITEMS_SIDE 640

typedef __attribute__((ext_vector_type(8))) __bf16 bf16x8;
typedef __attribute__((ext_vector_type(4))) float  f32x4;

__device__ __forceinline__ unsigned short f2bf(float f) {
  unsigned int u = __builtin_bit_cast(unsigned int, f);
  u += 0x7fffu + ((u >> 16) & 1u);          // round-to-nearest-even
  return (unsigned short)(u >> 16);
}
__device__ __forceinline__ float bf2f(unsigned short b) {
  return __builtin_bit_cast(float, (unsigned int)b << 16);
}

// async global->LDS, 16B per lane (linear LDS dest = wave base + lane*16)
__device__ __forceinline__ void async_copy16(const void* g, void* l) {
  __builtin_amdgcn_global_load_lds(
      (__attribute__((address_space(1))) void*)(g),
      (__attribute__((address_space(3))) void*)(l), 16, 0, 0);
}

// partial-slot prefix for 32-row q-block b (0..127): sum of (n_b'-1), b'<b,
// n_b = (b>>5)+1  (chunks of 32 tiles over total_t = b+1)
__device__ __forceinline__ int slot_prefix(int b) {
  if (b < 32) return 0;
  if (b < 64) return b - 32;
  if (b < 96) return 32 + 2 * (b - 64);
  return 96 + 3 * (b - 96);
}

// ------------------------------------------------- fused fp32->bf16 (3 srcs)
__global__ __launch_bounds__(256) void cvt_all(const float* __restrict__ a,
                                               const float* __restrict__ b,
                                               const float* __restrict__ c,
                                               unsigned short* __restrict__ out,
                                               int n1, int n2, int n3) {
  int i = blockIdx.x * 256 + threadIdx.x;         // float4 index
  const float* src;
  int off;
  if (i < n1)            { src = a; off = i; }
  else if (i < n1 + n2)  { src = b; off = i - n1; }
  else if (i < n1 + n2 + n3) { src = c; off = i - n1 - n2; }
  else return;
  float4 v = reinterpret_cast<const float4*>(src)[off];
  ushort4 o;
  o.x = f2bf(v.x); o.y = f2bf(v.y); o.z = f2bf(v.z); o.w = f2bf(v.w);
  reinterpret_cast<ushort4*>(out)[i] = o;
}

// ------------------------------------------------------- C = A(M,K) * B(N,K)^T
// 128x128 tile, BK=64, 4 waves as 2x2 of 64x64 (verified rounds 1-13)
// + bijective XCD blockIdx swizzle (both grids %8==0).
template <bool OUT_BF16>
__global__ __launch_bounds__(256) void gemm_bt(const unsigned short* __restrict__ A,
                                               const unsigned short* __restrict__ B,
                                               void* __restrict__ C,
                                               int M, int N, int K) {
  __shared__ __align__(16) unsigned short Als[128 * 64];
  __shared__ __align__(16) unsigned short Bls[128 * 64];
  const int t    = threadIdx.x;
  const int lane = t & 63;
  const int wid  = t >> 6;
  const int wr = wid >> 1, wc = wid & 1;
  const int l15 = lane & 15, lg = lane >> 4;

  const int nwg = gridDim.x * gridDim.y;
  const int lin = blockIdx.y * gridDim.x + blockIdx.x;
  const int swz = (lin & 7) * (nwg >> 3) + (lin >> 3);   // bijective (nwg%8==0)
  const int m0 = (swz / gridDim.x) * 128, n0 = (swz % gridDim.x) * 128;

  f32x4 acc[4][4] = {};

  for (int k0 = 0; k0 < K; k0 += 64) {
    __syncthreads();                                  // LDS reuse fence
#pragma unroll
    for (int i = 0; i < 4; ++i) {
      int c   = i * 256 + t;                          // 16B chunk index 0..1023
      int kc  = c >> 9;
      int row = (c >> 2) & 127;
      int j8  = (c & 3) ^ (row & 3);                  // inverse-swizzled source
      int gcol = k0 + kc * 32 + j8 * 8;
      async_copy16(A + (size_t)(m0 + row) * K + gcol, Als + c * 8);
      async_copy16(B + (size_t)(n0 + row) * K + gcol, Bls + c * 8);
    }
    __syncthreads();                                  // drains vmcnt before use
#pragma unroll
    for (int kc = 0; kc < 2; ++kc) {
      bf16x8 af[4], bfr[4];
#pragma unroll
      for (int m = 0; m < 4; ++m) {
        int row   = wr * 64 + m * 16 + l15;
        int chunk = kc * 512 + row * 4 + (lg ^ (row & 3));
        af[m] = *reinterpret_cast<const bf16x8*>(Als + chunk * 8);
      }
#pragma unroll
      for (int n = 0; n < 4; ++n) {
        int row   = wc * 64 + n * 16 + l15;
        int chunk = kc * 512 + row * 4 + (lg ^ (row & 3));
        bfr[n] = *reinterpret_cast<const bf16x8*>(Bls + chunk * 8);
      }
#pragma unroll
      for (int m = 0; m < 4; ++m)
#pragma unroll
        for (int n = 0; n < 4; ++n)
          acc[m][n] = __builtin_amdgcn_mfma_f32_16x16x32_bf16(af[m], bfr[n],
                                                              acc[m][n], 0, 0, 0);
    }
  }

#pragma unroll
  for (int m = 0; m < 4; ++m) {
#pragma unroll
    for (int n = 0; n < 4; ++n) {
      int col = n0 + wc * 64 + n * 16 + l15;
#pragma unroll
      for (int r = 0; r < 4; ++r) {
        int rowg = m0 + wr * 64 + m * 16 + lg * 4 + r;   // C/D: row=(l>>4)*4+r
        if constexpr (OUT_BF16)
          reinterpret_cast<unsigned short*>(C)[(size_t)rowg * N + col] =
              f2bf(acc[m][n][r]);
        else
          reinterpret_cast<float*>(C)[(size_t)rowg * N + col] = acc[m][n][r];
      }
    }
  }
}

// --------------------------------------------- RMSNorm + RoPE + layout split
// v -> staging-ready tiled layout: vtg[kvh][t=s>>5][slot=(s>>3)&3][d][s&7]
__global__ __launch_bounds__(256) void postproc(const unsigned short* __restrict__ qkv,
                                                const float* __restrict__ cosb,
                                                const float* __restrict__ sinb,
                                                unsigned short* __restrict__ q,
                                                unsigned short* __restrict__ k,
                                                unsigned short* __restrict__ vt) {
  const int wid = threadIdx.x >> 6, lane = threadIdx.x & 63;
  const int task = blockIdx.x * 4 + wid;          // 0 .. SEQ*12-1
  const int s = task / 12, comp = task % 12;

  ushort4 raw = reinterpret_cast<const ushort4*>(qkv + (size_t)task * 256)[lane];
  float x0 = bf2f(raw.x), x1 = bf2f(raw.y), x2 = bf2f(raw.z), x3 = bf2f(raw.w);

  float ss = x0 * x0 + x1 * x1 + x2 * x2 + x3 * x3;
#pragma unroll
  for (int m = 1; m < 64; m <<= 1) ss += __shfl_xor(ss, m);
  float inv = rsqrtf(ss * (1.0f / 256.0f) + 1e-6f);
  x0 *= inv; x1 *= inv; x2 *= inv; x3 *= inv;

  if (comp < 10) {  // RoPE: lane d-range 4*lane..4*lane+3, partner ±128
    float4 c  = reinterpret_cast<const float4*>(cosb + (size_t)s * 256)[lane];
    float4 sn = reinterpret_cast<const float4*>(sinb + (size_t)s * 256)[lane];
    float p0 = __shfl_xor(x0, 32), p1 = __shfl_xor(x1, 32);
    float p2 = __shfl_xor(x2, 32), p3 = __shfl_xor(x3, 32);
    float sg = (lane < 32) ? -1.0f : 1.0f;       // rotate_half sign
    x0 = x0 * c.x + sg * p0 * sn.x;
    x1 = x1 * c.y + sg * p1 * sn.y;
    x2 = x2 * c.z + sg * p2 * sn.z;
    x3 = x3 * c.w + sg * p3 * sn.w;
  }

  if (comp < 8) {
    ushort4 o;
    o.x = f2bf(x0 * SCAL); o.y = f2bf(x1 * SCAL);
    o.z = f2bf(x2 * SCAL); o.w = f2bf(x3 * SCAL);
    reinterpret_cast<ushort4*>(q + ((size_t)s * NHEADS + comp) * 256)[lane] = o;
  } else if (comp < 10) {
    ushort4 o;
    o.x = f2bf(x0); o.y = f2bf(x1); o.z = f2bf(x2); o.w = f2bf(x3);
    reinterpret_cast<ushort4*>(k + ((size_t)(comp - 8) * SEQ + s) * 256)[lane] = o;
  } else {  // v -> staging-ready tiled layout (16B chunk = 8 kv of one d)
    size_t base = (size_t)(comp - 10) * 1048576 + (size_t)(s >> 5) * 8192 +
                  (size_t)((s >> 3) & 3) * 2048 + (s & 7);
    int d0 = lane * 4;
    vt[base + (size_t)(d0 + 0) * 8] = f2bf(x0);
    vt[base + (size_t)(d0 + 1) * 8] = f2bf(x1);
    vt[base + (size_t)(d0 + 2) * 8] = f2bf(x2);
    vt[base + (size_t)(d0 + 3) * 8] = f2bf(x3);
  }
}

// --------------------------------------------------- causal flash attention
// v12: 4 barrier domains/CU.  Blocks shrink to 2 waves (128 thr) = one
// head-pair x 32 q-rows; K+V SINGLE-buffered (16+16 KB) + P 5 KB = 37.9 KB
// -> 4 blocks/CU (same 8 waves/CU, but 4 independent barrier domains; the
// single-buffer stage stall hides under the other 3 blocks' compute, which
// dbuf+2-domains could not achieve: r13 duty ~53% of the LDS-pipe floor).
// Items: (kvh, hpl, 32-row q-block b in 0..127, chunk j of 32 tiles,
// n_b=(b>>5)+1) = 640/side on 512 blocks/side, true-LPT order (full-32
// chunks desc b, then last-chunks desc length).  Per-wave machinery
// identical to r13 (head-paired swapped QK, K XOR-swz, V slot-major, lazy
// softmax, defer-max, P-LDS roundtrip, kvh->XCD two-ticket pinning).
__global__ __launch_bounds__(128, 2) void flash(const unsigned short* __restrict__ q,
                                                const unsigned short* __restrict__ k,
                                                const unsigned short* __restrict__ vtg,
                                                unsigned short* __restrict__ attn,
                                                unsigned short* __restrict__ opart,
                                                float* __restrict__ ml0,
                                                float* __restrict__ mlp,
                                                int* __restrict__ ticket) {
  extern __shared__ __align__(16) unsigned short lds[];
  unsigned short* Kls = lds;            // [32*256]  16 KB, XOR-swz
  unsigned short* Vls = lds + 8192;     // [4][256][8] 16 KB slot-major
  unsigned short* Pls = lds + 16384;    // [2 waves][2 heads][16][40]  5 KB
  __shared__ int s_item;

  const int tid  = threadIdx.x;
  const int lane = tid & 63, wid = tid >> 6;     // wid in {0,1}
  const int l15 = lane & 15, lg = lane >> 4;
  const int side = (blockIdx.x & 7) >> 2;        // XCD 0-3 -> kvh0, 4-7 -> kvh1
  const int kvh = side;

  const unsigned short* kbase  = k   + (size_t)kvh * SEQ * 256;
  const unsigned short* vstage = vtg + (size_t)kvh * 1048576;

  for (;;) {
    __syncthreads();                             // protect s_item / P reuse
    if (tid == 0) s_item = atomicAdd(ticket + side, 1);
    __syncthreads();
    const int it = s_item;
    if (it >= NITEMS_SIDE) break;

    // ---- TRUE-LPT decode (per side, 640 items):
    //  it   0..191: b=127..96, full chunks j=0..2  (6 items/b)
    //  it 192..319: b= 95..64, full chunks j=0..1  (4 items/b)
    //  it 320..383: b= 63..32, full chunk  j=0     (2 items/b)
    //  it 384..639: last-chunks desc length m=b&31 (31..0); per m: 8 items
    //               = 4 groups (b=g*32+m, j=g) x 2 hpl; length m+1.
    int b, hpl, j;
    if (it < 192)      { b = 127 - it / 6;             int r = it % 6; hpl = r / 3;  j = r % 3; }
    else if (it < 320) { int u = it - 192; b = 95 - (u >> 2); int r = u & 3; hpl = r >> 1; j = r & 1; }
    else if (it < 384) { int u = it - 320; b = 63 - (u >> 1); hpl = u & 1;   j = 0; }
    else               { int u = it - 384; int m31 = 31 - (u >> 3); int r = u & 7;
                         int g = r >> 1;   b = g * 32 + m31; hpl = r & 1;    j = g; }

    const int h0 = kvh * 4 + hpl * 2;            // this wave's head pair
    const int total_t = b + 1;                   // tiles of 32 kv
    const int t0 = j * 32;
    const int t1 = min(t0 + 32, total_t) - 1;
    const int qb = b * 32 + wid * 16;            // this wave's 16 q-rows

    // Q fragments, one per head of the pair
    bf16x8 qf[2][8];
#pragma unroll
    for (int g = 0; g < 2; ++g) {
      const unsigned short* qrow =
          q + ((size_t)(qb + l15) * NHEADS + h0 + g) * 256 + lg * 8;
#pragma unroll
      for (int kc = 0; kc < 8; ++kc)
        qf[g][kc] = *reinterpret_cast<const bf16x8*>(qrow + kc * 32);
    }

    f32x4 o[16][2];
#pragma unroll
    for (int i = 0; i < 16; ++i)
#pragma unroll
      for (int g = 0; g < 2; ++g) o[i][g] = f32x4{0.f, 0.f, 0.f, 0.f};
    float mr0 = -1e30f, lr0 = 0.f, mr1 = -1e30f, lr1 = 0.f;  // l = per-lane partial

    auto stage = [&](int t) {                    // 128 threads, 16 copies each
      const int kvb = t * 32;
#pragma unroll
      for (int i = 0; i < 8; ++i) {              // K: 1024 chunks of 16B
        int p = i * 128 + tid;
        int krow = p >> 5, pj = p & 31;
        int jj = (pj & ~7) | ((pj ^ krow) & 7);  // involution source swizzle
        async_copy16(kbase + (size_t)(kvb + krow) * 256 + jj * 8,
                     Kls + p * 8);
      }
      const unsigned short* vsrc = vstage + (size_t)t * 8192;
#pragma unroll
      for (int i = 0; i < 8; ++i) {              // V: 1024 chunks, linear
        int p = i * 128 + tid;
        async_copy16(vsrc + p * 8, Vls + p * 8);
      }
    };

    stage(t0);
    __syncthreads();                             // drains vmcnt(0)

    for (int t = t0; t <= t1; ++t) {
      const int kvb = t * 32;

      if (kvb <= qb + 15) {                      // skip fully-masked waves
        // ---- S^T[kv,q] = K.Q^T, both heads share each kf read
        f32x4 s[2][2] = {};
        __builtin_amdgcn_s_setprio(1);
#pragma unroll
        for (int n = 0; n < 2; ++n) {
          const int row = n * 16 + l15;
#pragma unroll
          for (int kc = 0; kc < 8; ++kc) {
            int jj = kc * 4 + lg;
            int pj = (jj & ~7) | ((jj ^ row) & 7);
            bf16x8 kf = *reinterpret_cast<const bf16x8*>(Kls + (row * 32 + pj) * 8);
            s[0][n] = __builtin_amdgcn_mfma_f32_16x16x32_bf16(kf, qf[0][kc], s[0][n], 0, 0, 0);
            s[1][n] = __builtin_amdgcn_mfma_f32_16x16x32_bf16(kf, qf[1][kc], s[1][n], 0, 0, 0);
          }
        }
        __builtin_amdgcn_s_setprio(0);

        // causal mask: same (kv,q) geometry for both heads
        if (kvb + 31 > qb) {
#pragma unroll
          for (int n = 0; n < 2; ++n)
#pragma unroll
            for (int r = 0; r < 4; ++r)
              if (kvb + n * 16 + lg * 4 + r > qb + l15) {
                s[0][n][r] = -1e30f;
                s[1][n][r] = -1e30f;
              }
        }

        // ---- lazy online softmax (lane-local maxima; shuffles only on the
        // rare defer-max trigger; union over lanes == union over rows)
        float pm0 = fmaxf(fmaxf(fmaxf(s[0][0][0], s[0][0][1]), fmaxf(s[0][0][2], s[0][0][3])),
                          fmaxf(fmaxf(s[0][1][0], s[0][1][1]), fmaxf(s[0][1][2], s[0][1][3])));
        float pm1 = fmaxf(fmaxf(fmaxf(s[1][0][0], s[1][0][1]), fmaxf(s[1][0][2], s[1][0][3])),
                          fmaxf(fmaxf(s[1][1][0], s[1][1][1]), fmaxf(s[1][1][2], s[1][1][3])));

        if (__any(fmaxf(pm0 - mr0, pm1 - mr1) > 8.0f)) {   // defer-max (THR=8)
          float q0 = fmaxf(mr0, pm0), q1 = fmaxf(mr1, pm1);
          q0 = fmaxf(q0, __shfl_xor(q0, 16));
          q0 = fmaxf(q0, __shfl_xor(q0, 32));
          q1 = fmaxf(q1, __shfl_xor(q1, 16));
          q1 = fmaxf(q1, __shfl_xor(q1, 32));
          float sc0 = __expf(mr0 - q0), sc1 = __expf(mr1 - q1);
#pragma unroll
          for (int i = 0; i < 16; ++i)
#pragma unroll
            for (int r = 0; r < 4; ++r) {
              o[i][0][r] *= sc0;
              o[i][1][r] *= sc1;
            }
          lr0 *= sc0; lr1 *= sc1;
          mr0 = q0;   mr1 = q1;
        }

#pragma unroll
        for (int n = 0; n < 2; ++n)
#pragma unroll
          for (int r = 0; r < 4; ++r) {
            s[0][n][r] = __expf(s[0][n][r] - mr0);
            s[1][n][r] = __expf(s[1][n][r] - mr1);
          }

        lr0 += ((s[0][0][0] + s[0][0][1]) + (s[0][0][2] + s[0][0][3])) +
               ((s[0][1][0] + s[0][1][1]) + (s[0][1][2] + s[0][1][3]));
        lr1 += ((s[1][0][0] + s[1][0][1]) + (s[1][0][2] + s[1][0][3])) +
               ((s[1][1][0] + s[1][1][1]) + (s[1][1][2] + s[1][1][3]));

        // P[q=l15][kv] per head -> per-wave LDS rows (pad 40)
#pragma unroll
        for (int g = 0; g < 2; ++g) {
          unsigned short* Pr = Pls + ((wid * 2 + g) * 16 + l15) * 40;
#pragma unroll
          for (int n = 0; n < 2; ++n) {
            ushort4 w;
            w.x = f2bf(s[g][n][0]); w.y = f2bf(s[g][n][1]);
            w.z = f2bf(s[g][n][2]); w.w = f2bf(s[g][n][3]);
            *reinterpret_cast<ushort4*>(Pr + n * 16 + lg * 4) = w;
          }
        }
        asm volatile("s_waitcnt lgkmcnt(0)" ::: "memory");
        __builtin_amdgcn_sched_barrier(0);

        // ---- O^T[d,q] += V^T.P^T, both heads share each vf read
        bf16x8 pb0 = *reinterpret_cast<const bf16x8*>(
            Pls + ((wid * 2 + 0) * 16 + l15) * 40 + lg * 8);
        bf16x8 pb1 = *reinterpret_cast<const bf16x8*>(
            Pls + ((wid * 2 + 1) * 16 + l15) * 40 + lg * 8);
        __builtin_amdgcn_s_setprio(1);
#pragma unroll
        for (int dt = 0; dt < 16; ++dt) {
          bf16x8 vf = *reinterpret_cast<const bf16x8*>(
              Vls + ((lg << 8) + dt * 16 + l15) * 8);
          o[dt][0] = __builtin_amdgcn_mfma_f32_16x16x32_bf16(vf, pb0, o[dt][0], 0, 0, 0);
          o[dt][1] = __builtin_amdgcn_mfma_f32_16x16x32_bf16(vf, pb1, o[dt][1], 0, 0, 0);
        }
        __builtin_amdgcn_s_setprio(0);
      }

      __syncthreads();                           // all waves done reading tile
      if (t < t1) {
        stage(t + 1);                            // overwrite single buffer
        __syncthreads();                         // drain (vmcnt 0)
      }
    }

    // ---- reduce per-lane l partials to row sums (once per item)
    lr0 += __shfl_xor(lr0, 16); lr0 += __shfl_xor(lr0, 32);
    lr1 += __shfl_xor(lr1, 16); lr1 += __shfl_xor(lr1, 32);

    // ---- epilogue: lane holds O^T[d = dt*16+lg*4+r, q = qb+l15] per head
    const int qrow = qb + l15;
#pragma unroll
    for (int g = 0; g < 2; ++g) {
      const int head = h0 + g;
      const float mg = g ? mr1 : mr0;
      const float lg_ = g ? lr1 : lr0;
      if (j == 0) {
#pragma unroll
        for (int dt = 0; dt < 16; ++dt) {
          ushort4 w;
          w.x = f2bf(o[dt][g][0]); w.y = f2bf(o[dt][g][1]);
          w.z = f2bf(o[dt][g][2]); w.w = f2bf(o[dt][g][3]);
          *reinterpret_cast<ushort4*>(
              attn + (size_t)qrow * HID + head * 256 + dt * 16 + lg * 4) = w;
        }
        if (lg == 0)
          reinterpret_cast<float2*>(ml0)[head * SEQ + qrow] = float2{mg, lg_};
      } else {
        const int p = slot_prefix(b) + (j - 1);  // 0..191
        const size_t prow = ((size_t)head * 192 + p) * 32 + (qrow & 31);
#pragma unroll
        for (int dt = 0; dt < 16; ++dt) {
          ushort4 w;
          w.x = f2bf(o[dt][g][0]); w.y = f2bf(o[dt][g][1]);
          w.z = f2bf(o[dt][g][2]); w.w = f2bf(o[dt][g][3]);
          *reinterpret_cast<ushort4*>(opart + prow * 256 + dt * 16 + lg * 4) = w;
        }
        if (lg == 0) reinterpret_cast<float2*>(mlp)[prow] = float2{mg, lg_};
      }
    }
  }
}

// ----------------------------------------------------- split-KV merge pass
// row s (q-block b = s>>5) has n = (b>>5)+1 partials: chunk0 in attn/ml0,
// chunks 1..n-1 in opart/mlp at slots prefix(b)+j-1.
__global__ __launch_bounds__(256) void merge(const unsigned short* __restrict__ opart,
                                             const float* __restrict__ ml0,
                                             const float* __restrict__ mlp,
                                             unsigned short* __restrict__ attn) {
  const int wid = threadIdx.x >> 6, lane = threadIdx.x & 63;
  const int rid = blockIdx.x * 4 + wid;           // 0..32767 = h*4096 + s
  const int h = rid >> 12, s = rid & 4095;
  const int b = s >> 5;
  const int n = (b >> 5) + 1;

  float2 m_l[4];
  m_l[0] = reinterpret_cast<const float2*>(ml0)[rid];
  const int pf = slot_prefix(b);
  size_t prow[4];
  for (int jj = 1; jj < n; ++jj) {
    prow[jj] = ((size_t)h * 192 + pf + jj - 1) * 32 + (s & 31);
    m_l[jj] = reinterpret_cast<const float2*>(mlp)[prow[jj]];
  }

  float M = m_l[0].x;
  for (int jj = 1; jj < n; ++jj) M = fmaxf(M, m_l[jj].x);
  float w[4], L = 0.f;
  for (int jj = 0; jj < n; ++jj) {
    w[jj] = __expf(m_l[jj].x - M);
    L += w[jj] * m_l[jj].y;
  }
  float invL = 1.0f / L;
  for (int jj = 0; jj < n; ++jj) w[jj] *= invL;

  unsigned short* arow = attn + (size_t)s * HID + h * 256;
  ushort4 a = reinterpret_cast<const ushort4*>(arow)[lane];
  float acc0 = w[0] * bf2f(a.x), acc1 = w[0] * bf2f(a.y);
  float acc2 = w[0] * bf2f(a.z), acc3 = w[0] * bf2f(a.w);
  for (int jj = 1; jj < n; ++jj) {
    ushort4 bq = reinterpret_cast<const ushort4*>(opart + prow[jj] * 256)[lane];
    acc0 += w[jj] * bf2f(bq.x); acc1 += w[jj] * bf2f(bq.y);
    acc2 += w[jj] * bf2f(bq.z); acc3 += w[jj] * bf2f(bq.w);
  }
  ushort4 o;
  o.x = f2bf(acc0); o.y = f2bf(acc1); o.z = f2bf(acc2); o.w = f2bf(acc3);
  reinterpret_cast<ushort4*>(arow)[lane] = o;
}

// ---------------------------------------------------------------- launcher
extern "C" void kernel_launch(void* const* d_in, const int* in_sizes, int n_in,
                              void* d_out, int out_size, void* d_ws, size_t ws_size,
                              hipStream_t stream) {
  const float* hs   = (const float*)d_in[0];
  const float* cosb = (const float*)d_in[1];
  const float* sinb = (const float*)d_in[2];
  const float* qkvw = (const float*)d_in[3];
  const float* ow   = (const float*)d_in[4];

  char* ws = (char*)d_ws;
  unsigned short* hs_bf   = (unsigned short*)(ws + 0);           // 16 MB (dead after QKV GEMM)
  unsigned short* wqkv_bf = (unsigned short*)(ws + 16777216);    // 12 MB (dead after QKV GEMM)
  unsigned short* wo_bf   = (unsigned short*)(ws + 29360128);    //  8 MB (live till final GEMM)
  unsigned short* qkv_bf  = (unsigned short*)(ws + 37748736);    // 24 MB (dead after postproc)
  unsigned short* attn_bf = qkv_bf;                              // 16 MB overlay
  unsigned short* q_bf    = (unsigned short*)(ws + 62914560);    // 16 MB
  unsigned short* k_bf    = (unsigned short*)(ws + 79691776);    //  4 MB
  unsigned short* vt_bf   = (unsigned short*)(ws + 83886080);    //  4 MB (staging-ready layout)
  // flash partial overlays (regions dead after the QKV GEMM):
  unsigned short* opart   = (unsigned short*)(ws + 0);           // 8h*192*32*512B = 24 MB
  float*          ml0buf  = (float*)(ws + 25165824);             // 256 KB (32768 float2)
  float*          mlpbuf  = (float*)(ws + 25427968);             // 384 KB (49152 float2)
  int*            ticket  = (int*)(ws + 25821184);               // 8 B (2 sides)

  const int n1 = SEQ * HID / 4, n2 = QKVN * HID / 4, n3 = HID * HID / 4;
  cvt_all<<<dim3((n1 + n2 + n3 + 255) / 256), dim3(256), 0, stream>>>(
      hs, qkvw, ow, hs_bf, n1, n2, n3);

  gemm_bt<true><<<dim3(QKVN / 128, SEQ / 128), dim3(256), 0, stream>>>(
      hs_bf, wqkv_bf, qkv_bf, SEQ, QKVN, HID);

  postproc<<<dim3(SEQ * 12 / 4), dim3(256), 0, stream>>>(qkv_bf, cosb, sinb, q_bf, k_bf, vt_bf);

  hipMemsetAsync(ticket, 0, 8, stream);

  flash<<<dim3(1024), dim3(128), 37888, stream>>>(q_bf, k_bf, vt_bf, attn_bf,
                                                  opart, ml0buf, mlpbuf, ticket);

  merge<<<dim3(8192), dim3(256), 0, stream>>>(opart, ml0buf, mlpbuf, attn_bf);

  gemm_bt<false><<<dim3(HID / 128, SEQ / 128), dim3(256), 0, stream>>>(
      attn_bf, wo_bf, d_out, SEQ, HID, HID);
}

// Round 15
// 291.863 us; speedup vs baseline: 1.2527x; 1.2527x over previous
//
#include <hip/hip_runtime.h>

// Problem constants (fixed by the reference)
#define NHEADS 8
#define NKVH   2
#define HD     256
#define SEQ    4096
#define HID    2048
#define QKVN   3072   // (NH + 2*NKV) * D
#define SCAL   (1.0f/256.0f)
#define NITEMS_SIDE 320

typedef __attribute__((ext_vector_type(8))) __bf16 bf16x8;
typedef __attribute__((ext_vector_type(4))) float  f32x4;

__device__ __forceinline__ unsigned short f2bf(float f) {
  unsigned int u = __builtin_bit_cast(unsigned int, f);
  u += 0x7fffu + ((u >> 16) & 1u);          // round-to-nearest-even
  return (unsigned short)(u >> 16);
}
__device__ __forceinline__ float bf2f(unsigned short b) {
  return __builtin_bit_cast(float, (unsigned int)b << 16);
}

// async global->LDS, 16B per lane (linear LDS dest = wave base + lane*16)
__device__ __forceinline__ void async_copy16(const void* g, void* l) {
  __builtin_amdgcn_global_load_lds(
      (__attribute__((address_space(1))) void*)(g),
      (__attribute__((address_space(3))) void*)(l), 16, 0, 0);
}

// partial-slot prefix for 64-row q-block b (0..63): sum of (n_b'-1), b'<b,
// n_b = (b>>4)+1  (chunks of 32 tiles over total_t = 2b+2)
__device__ __forceinline__ int slot_prefix(int b) {
  if (b < 16) return 0;
  if (b < 32) return b - 16;
  if (b < 48) return 16 + 2 * (b - 32);
  return 48 + 3 * (b - 48);
}

// ------------------------------------------------- fused fp32->bf16 (3 srcs)
__global__ __launch_bounds__(256) void cvt_all(const float* __restrict__ a,
                                               const float* __restrict__ b,
                                               const float* __restrict__ c,
                                               unsigned short* __restrict__ out,
                                               int n1, int n2, int n3) {
  int i = blockIdx.x * 256 + threadIdx.x;         // float4 index
  const float* src;
  int off;
  if (i < n1)            { src = a; off = i; }
  else if (i < n1 + n2)  { src = b; off = i - n1; }
  else if (i < n1 + n2 + n3) { src = c; off = i - n1 - n2; }
  else return;
  float4 v = reinterpret_cast<const float4*>(src)[off];
  ushort4 o;
  o.x = f2bf(v.x); o.y = f2bf(v.y); o.z = f2bf(v.z); o.w = f2bf(v.w);
  reinterpret_cast<ushort4*>(out)[i] = o;
}

// ------------------------------------------------------- C = A(M,K) * B(N,K)^T
// 128x128 tile, BK=64, 4 waves as 2x2 of 64x64 (verified rounds 1-13)
// + bijective XCD blockIdx swizzle (both grids %8==0).
template <bool OUT_BF16>
__global__ __launch_bounds__(256) void gemm_bt(const unsigned short* __restrict__ A,
                                               const unsigned short* __restrict__ B,
                                               void* __restrict__ C,
                                               int M, int N, int K) {
  __shared__ __align__(16) unsigned short Als[128 * 64];
  __shared__ __align__(16) unsigned short Bls[128 * 64];
  const int t    = threadIdx.x;
  const int lane = t & 63;
  const int wid  = t >> 6;
  const int wr = wid >> 1, wc = wid & 1;
  const int l15 = lane & 15, lg = lane >> 4;

  const int nwg = gridDim.x * gridDim.y;
  const int lin = blockIdx.y * gridDim.x + blockIdx.x;
  const int swz = (lin & 7) * (nwg >> 3) + (lin >> 3);   // bijective (nwg%8==0)
  const int m0 = (swz / gridDim.x) * 128, n0 = (swz % gridDim.x) * 128;

  f32x4 acc[4][4] = {};

  for (int k0 = 0; k0 < K; k0 += 64) {
    __syncthreads();                                  // LDS reuse fence
#pragma unroll
    for (int i = 0; i < 4; ++i) {
      int c   = i * 256 + t;                          // 16B chunk index 0..1023
      int kc  = c >> 9;
      int row = (c >> 2) & 127;
      int j8  = (c & 3) ^ (row & 3);                  // inverse-swizzled source
      int gcol = k0 + kc * 32 + j8 * 8;
      async_copy16(A + (size_t)(m0 + row) * K + gcol, Als + c * 8);
      async_copy16(B + (size_t)(n0 + row) * K + gcol, Bls + c * 8);
    }
    __syncthreads();                                  // drains vmcnt before use
#pragma unroll
    for (int kc = 0; kc < 2; ++kc) {
      bf16x8 af[4], bfr[4];
#pragma unroll
      for (int m = 0; m < 4; ++m) {
        int row   = wr * 64 + m * 16 + l15;
        int chunk = kc * 512 + row * 4 + (lg ^ (row & 3));
        af[m] = *reinterpret_cast<const bf16x8*>(Als + chunk * 8);
      }
#pragma unroll
      for (int n = 0; n < 4; ++n) {
        int row   = wc * 64 + n * 16 + l15;
        int chunk = kc * 512 + row * 4 + (lg ^ (row & 3));
        bfr[n] = *reinterpret_cast<const bf16x8*>(Bls + chunk * 8);
      }
#pragma unroll
      for (int m = 0; m < 4; ++m)
#pragma unroll
        for (int n = 0; n < 4; ++n)
          acc[m][n] = __builtin_amdgcn_mfma_f32_16x16x32_bf16(af[m], bfr[n],
                                                              acc[m][n], 0, 0, 0);
    }
  }

#pragma unroll
  for (int m = 0; m < 4; ++m) {
#pragma unroll
    for (int n = 0; n < 4; ++n) {
      int col = n0 + wc * 64 + n * 16 + l15;
#pragma unroll
      for (int r = 0; r < 4; ++r) {
        int rowg = m0 + wr * 64 + m * 16 + lg * 4 + r;   // C/D: row=(l>>4)*4+r
        if constexpr (OUT_BF16)
          reinterpret_cast<unsigned short*>(C)[(size_t)rowg * N + col] =
              f2bf(acc[m][n][r]);
        else
          reinterpret_cast<float*>(C)[(size_t)rowg * N + col] = acc[m][n][r];
      }
    }
  }
}

// --------------------------------------------- RMSNorm + RoPE + layout split
// v -> staging-ready tiled layout: vtg[kvh][t=s>>5][slot=(s>>3)&3][d][s&7]
__global__ __launch_bounds__(256) void postproc(const unsigned short* __restrict__ qkv,
                                                const float* __restrict__ cosb,
                                                const float* __restrict__ sinb,
                                                unsigned short* __restrict__ q,
                                                unsigned short* __restrict__ k,
                                                unsigned short* __restrict__ vt) {
  const int wid = threadIdx.x >> 6, lane = threadIdx.x & 63;
  const int task = blockIdx.x * 4 + wid;          // 0 .. SEQ*12-1
  const int s = task / 12, comp = task % 12;

  ushort4 raw = reinterpret_cast<const ushort4*>(qkv + (size_t)task * 256)[lane];
  float x0 = bf2f(raw.x), x1 = bf2f(raw.y), x2 = bf2f(raw.z), x3 = bf2f(raw.w);

  float ss = x0 * x0 + x1 * x1 + x2 * x2 + x3 * x3;
#pragma unroll
  for (int m = 1; m < 64; m <<= 1) ss += __shfl_xor(ss, m);
  float inv = rsqrtf(ss * (1.0f / 256.0f) + 1e-6f);
  x0 *= inv; x1 *= inv; x2 *= inv; x3 *= inv;

  if (comp < 10) {  // RoPE: lane d-range 4*lane..4*lane+3, partner ±128
    float4 c  = reinterpret_cast<const float4*>(cosb + (size_t)s * 256)[lane];
    float4 sn = reinterpret_cast<const float4*>(sinb + (size_t)s * 256)[lane];
    float p0 = __shfl_xor(x0, 32), p1 = __shfl_xor(x1, 32);
    float p2 = __shfl_xor(x2, 32), p3 = __shfl_xor(x3, 32);
    float sg = (lane < 32) ? -1.0f : 1.0f;       // rotate_half sign
    x0 = x0 * c.x + sg * p0 * sn.x;
    x1 = x1 * c.y + sg * p1 * sn.y;
    x2 = x2 * c.z + sg * p2 * sn.z;
    x3 = x3 * c.w + sg * p3 * sn.w;
  }

  if (comp < 8) {
    ushort4 o;
    o.x = f2bf(x0 * SCAL); o.y = f2bf(x1 * SCAL);
    o.z = f2bf(x2 * SCAL); o.w = f2bf(x3 * SCAL);
    reinterpret_cast<ushort4*>(q + ((size_t)s * NHEADS + comp) * 256)[lane] = o;
  } else if (comp < 10) {
    ushort4 o;
    o.x = f2bf(x0); o.y = f2bf(x1); o.z = f2bf(x2); o.w = f2bf(x3);
    reinterpret_cast<ushort4*>(k + ((size_t)(comp - 8) * SEQ + s) * 256)[lane] = o;
  } else {  // v -> staging-ready tiled layout (16B chunk = 8 kv of one d)
    size_t base = (size_t)(comp - 10) * 1048576 + (size_t)(s >> 5) * 8192 +
                  (size_t)((s >> 3) & 3) * 2048 + (s & 7);
    int d0 = lane * 4;
    vt[base + (size_t)(d0 + 0) * 8] = f2bf(x0);
    vt[base + (size_t)(d0 + 1) * 8] = f2bf(x1);
    vt[base + (size_t)(d0 + 2) * 8] = f2bf(x2);
    vt[base + (size_t)(d0 + 3) * 8] = f2bf(x3);
  }
}

// --------------------------------------------------- causal flash attention
// v13 = r13 (best measured: head-paired 4-wave blocks, dbuf K/V LDS, ticket
// true-LPT, lazy softmax, kvh->XCD pinning) + normalize-in-epilogue for
// single-partial rows (b<16): their merge was a pure 1/L scale, now folded
// here; merge only covers s>=1024.  All else byte-identical to r13.
__global__ __launch_bounds__(256, 2) void flash(const unsigned short* __restrict__ q,
                                                const unsigned short* __restrict__ k,
                                                const unsigned short* __restrict__ vtg,
                                                unsigned short* __restrict__ attn,
                                                unsigned short* __restrict__ opart,
                                                float* __restrict__ ml0,
                                                float* __restrict__ mlp,
                                                int* __restrict__ ticket) {
  extern __shared__ __align__(16) unsigned short lds[];
  unsigned short* Kls = lds;            // [2][32*256]  2 x 16 KB, XOR-swz
  unsigned short* Vls = lds + 16384;    // [2][4][256][8] 2 x 16 KB slot-major
  unsigned short* Pls = lds + 32768;    // [4 waves][2 grp][16 q][40]  10 KB
  __shared__ int s_item;

  const int tid  = threadIdx.x;
  const int lane = tid & 63, wid = tid >> 6;
  const int l15 = lane & 15, lg = lane >> 4;
  const int side = (blockIdx.x & 7) >> 2;        // XCD 0-3 -> kvh0, 4-7 -> kvh1
  const int kvh = side;

  const unsigned short* kbase  = k   + (size_t)kvh * SEQ * 256;
  const unsigned short* vstage = vtg + (size_t)kvh * 1048576;

  for (;;) {
    __syncthreads();                             // protect s_item rewrite
    if (tid == 0) s_item = atomicAdd(ticket + side, 1);
    __syncthreads();
    const int it = s_item;
    if (it >= NITEMS_SIDE) break;

    // ---- TRUE-LPT decode (per side):
    //  it   0.. 95: b=63..48, full chunks j=0..2   (6 items/b: 2 hpl x 3 j)
    //  it  96..159: b=47..32, full chunks j=0..1   (4 items/b)
    //  it 160..191: b=31..16, full chunk  j=0      (2 items/b)
    //  it 192..319: last-chunks by desc length m=b&15 (15..0); per m: 8 items
    //               = 4 b-groups (b=g*16+m, j=g) x 2 hpl; length 2m+2.
    int b, hpl, j;
    if (it < 96)       { b = 63 - it / 6;              int r = it % 6; hpl = r / 3;  j = r % 3; }
    else if (it < 160) { int u = it - 96;  b = 47 - (u >> 2); int r = u & 3; hpl = r >> 1; j = r & 1; }
    else if (it < 192) { int u = it - 160; b = 31 - (u >> 1); hpl = u & 1;   j = 0; }
    else               { int u = it - 192; int m15 = 15 - (u >> 3); int r = u & 7;
                         int g = r >> 1;   b = g * 16 + m15; hpl = r & 1;    j = g; }

    const int h0 = kvh * 4 + hpl * 2;            // this wave's head pair
    const int total_t = 2 * b + 2;               // tiles of 32 kv
    const int t0 = j * 32;
    const int t1 = min(t0 + 32, total_t) - 1;
    const int qb = b * 64 + wid * 16;            // this wave's 16 q-rows

    // Q fragments, one per head of the pair
    bf16x8 qf[2][8];
#pragma unroll
    for (int g = 0; g < 2; ++g) {
      const unsigned short* qrow =
          q + ((size_t)(qb + l15) * NHEADS + h0 + g) * 256 + lg * 8;
#pragma unroll
      for (int kc = 0; kc < 8; ++kc)
        qf[g][kc] = *reinterpret_cast<const bf16x8*>(qrow + kc * 32);
    }

    f32x4 o[16][2];
#pragma unroll
    for (int i = 0; i < 16; ++i)
#pragma unroll
      for (int g = 0; g < 2; ++g) o[i][g] = f32x4{0.f, 0.f, 0.f, 0.f};
    float mr0 = -1e30f, lr0 = 0.f, mr1 = -1e30f, lr1 = 0.f;  // l = per-lane partial

    auto stage = [&](int bb, int t) {
      const int kvb = t * 32;
#pragma unroll
      for (int i = 0; i < 4; ++i) {              // K: 1024 chunks of 16B
        int p = i * 256 + tid;
        int krow = p >> 5, pj = p & 31;
        int jj = (pj & ~7) | ((pj ^ krow) & 7);  // involution source swizzle
        async_copy16(kbase + (size_t)(kvb + krow) * 256 + jj * 8,
                     Kls + bb * 8192 + p * 8);
      }
      const unsigned short* vsrc = vstage + (size_t)t * 8192;
#pragma unroll
      for (int i = 0; i < 4; ++i) {              // V: 1024 chunks, linear
        int p = i * 256 + tid;
        async_copy16(vsrc + p * 8, Vls + bb * 8192 + p * 8);
      }
    };

    int cur = 0;
    stage(0, t0);
    __syncthreads();                             // drains vmcnt(0)

    for (int t = t0; t <= t1; ++t) {
      const int kvb = t * 32;
      if (t + 1 <= t1) stage(cur ^ 1, t + 1);    // async prefetch next tile

      if (kvb <= qb + 15) {                      // skip fully-masked waves
        const unsigned short* Kc = Kls + cur * 8192;
        const unsigned short* Vc = Vls + cur * 8192;

        // ---- S^T[kv,q] = K.Q^T, both heads share each kf read
        f32x4 s[2][2] = {};
        __builtin_amdgcn_s_setprio(1);
#pragma unroll
        for (int n = 0; n < 2; ++n) {
          const int row = n * 16 + l15;
#pragma unroll
          for (int kc = 0; kc < 8; ++kc) {
            int jj = kc * 4 + lg;
            int pj = (jj & ~7) | ((jj ^ row) & 7);
            bf16x8 kf = *reinterpret_cast<const bf16x8*>(Kc + (row * 32 + pj) * 8);
            s[0][n] = __builtin_amdgcn_mfma_f32_16x16x32_bf16(kf, qf[0][kc], s[0][n], 0, 0, 0);
            s[1][n] = __builtin_amdgcn_mfma_f32_16x16x32_bf16(kf, qf[1][kc], s[1][n], 0, 0, 0);
          }
        }
        __builtin_amdgcn_s_setprio(0);

        // causal mask: same (kv,q) geometry for both heads
        if (kvb + 31 > qb) {
#pragma unroll
          for (int n = 0; n < 2; ++n)
#pragma unroll
            for (int r = 0; r < 4; ++r)
              if (kvb + n * 16 + lg * 4 + r > qb + l15) {
                s[0][n][r] = -1e30f;
                s[1][n][r] = -1e30f;
              }
        }

        // ---- lazy online softmax: lane-LOCAL maxima; cross-lane shuffles
        // only when the defer-max trigger fires (union over lanes == union
        // over rows, so the __any trigger is exact).
        float pm0 = fmaxf(fmaxf(fmaxf(s[0][0][0], s[0][0][1]), fmaxf(s[0][0][2], s[0][0][3])),
                          fmaxf(fmaxf(s[0][1][0], s[0][1][1]), fmaxf(s[0][1][2], s[0][1][3])));
        float pm1 = fmaxf(fmaxf(fmaxf(s[1][0][0], s[1][0][1]), fmaxf(s[1][0][2], s[1][0][3])),
                          fmaxf(fmaxf(s[1][1][0], s[1][1][1]), fmaxf(s[1][1][2], s[1][1][3])));

        if (__any(fmaxf(pm0 - mr0, pm1 - mr1) > 8.0f)) {   // defer-max (THR=8)
          float q0 = fmaxf(mr0, pm0), q1 = fmaxf(mr1, pm1);
          q0 = fmaxf(q0, __shfl_xor(q0, 16));
          q0 = fmaxf(q0, __shfl_xor(q0, 32));
          q1 = fmaxf(q1, __shfl_xor(q1, 16));
          q1 = fmaxf(q1, __shfl_xor(q1, 32));
          float sc0 = __expf(mr0 - q0), sc1 = __expf(mr1 - q1);
#pragma unroll
          for (int i = 0; i < 16; ++i)
#pragma unroll
            for (int r = 0; r < 4; ++r) {
              o[i][0][r] *= sc0;
              o[i][1][r] *= sc1;
            }
          lr0 *= sc0; lr1 *= sc1;
          mr0 = q0;   mr1 = q1;
        }

#pragma unroll
        for (int n = 0; n < 2; ++n)
#pragma unroll
          for (int r = 0; r < 4; ++r) {
            s[0][n][r] = __expf(s[0][n][r] - mr0);
            s[1][n][r] = __expf(s[1][n][r] - mr1);
          }

        lr0 += ((s[0][0][0] + s[0][0][1]) + (s[0][0][2] + s[0][0][3])) +
               ((s[0][1][0] + s[0][1][1]) + (s[0][1][2] + s[0][1][3]));
        lr1 += ((s[1][0][0] + s[1][0][1]) + (s[1][0][2] + s[1][0][3])) +
               ((s[1][1][0] + s[1][1][1]) + (s[1][1][2] + s[1][1][3]));

        // P[q=l15][kv] per head -> per-wave LDS rows (pad 40)
#pragma unroll
        for (int g = 0; g < 2; ++g) {
          unsigned short* Pr = Pls + ((wid * 2 + g) * 16 + l15) * 40;
#pragma unroll
          for (int n = 0; n < 2; ++n) {
            ushort4 w;
            w.x = f2bf(s[g][n][0]); w.y = f2bf(s[g][n][1]);
            w.z = f2bf(s[g][n][2]); w.w = f2bf(s[g][n][3]);
            *reinterpret_cast<ushort4*>(Pr + n * 16 + lg * 4) = w;
          }
        }
        asm volatile("s_waitcnt lgkmcnt(0)" ::: "memory");
        __builtin_amdgcn_sched_barrier(0);

        // ---- O^T[d,q] += V^T.P^T, both heads share each vf read
        bf16x8 pb0 = *reinterpret_cast<const bf16x8*>(
            Pls + ((wid * 2 + 0) * 16 + l15) * 40 + lg * 8);
        bf16x8 pb1 = *reinterpret_cast<const bf16x8*>(
            Pls + ((wid * 2 + 1) * 16 + l15) * 40 + lg * 8);
        __builtin_amdgcn_s_setprio(1);
#pragma unroll
        for (int dt = 0; dt < 16; ++dt) {
          bf16x8 vf = *reinterpret_cast<const bf16x8*>(
              Vc + ((lg << 8) + dt * 16 + l15) * 8);
          o[dt][0] = __builtin_amdgcn_mfma_f32_16x16x32_bf16(vf, pb0, o[dt][0], 0, 0, 0);
          o[dt][1] = __builtin_amdgcn_mfma_f32_16x16x32_bf16(vf, pb1, o[dt][1], 0, 0, 0);
        }
        __builtin_amdgcn_s_setprio(0);
      }

      __syncthreads();                           // drain prefetch + LDS reuse
      cur ^= 1;
    }

    // ---- reduce per-lane l partials to row sums (once per item)
    lr0 += __shfl_xor(lr0, 16); lr0 += __shfl_xor(lr0, 32);
    lr1 += __shfl_xor(lr1, 16); lr1 += __shfl_xor(lr1, 32);

    // ---- epilogue: lane holds O^T[d = dt*16+lg*4+r, q = qb+l15] per head
    const int qrow = qb + l15;
#pragma unroll
    for (int g = 0; g < 2; ++g) {
      const int head = h0 + g;
      const float mg = g ? mr1 : mr0;
      const float lg_ = g ? lr1 : lr0;
      if (j == 0 && b < 16) {
        // single-partial row: normalize here; merge skips s<1024
        const float inv = 1.0f / lg_;
#pragma unroll
        for (int dt = 0; dt < 16; ++dt) {
          ushort4 w;
          w.x = f2bf(o[dt][g][0] * inv); w.y = f2bf(o[dt][g][1] * inv);
          w.z = f2bf(o[dt][g][2] * inv); w.w = f2bf(o[dt][g][3] * inv);
          *reinterpret_cast<ushort4*>(
              attn + (size_t)qrow * HID + head * 256 + dt * 16 + lg * 4) = w;
        }
      } else if (j == 0) {
#pragma unroll
        for (int dt = 0; dt < 16; ++dt) {
          ushort4 w;
          w.x = f2bf(o[dt][g][0]); w.y = f2bf(o[dt][g][1]);
          w.z = f2bf(o[dt][g][2]); w.w = f2bf(o[dt][g][3]);
          *reinterpret_cast<ushort4*>(
              attn + (size_t)qrow * HID + head * 256 + dt * 16 + lg * 4) = w;
        }
        if (lg == 0)
          reinterpret_cast<float2*>(ml0)[head * SEQ + qrow] = float2{mg, lg_};
      } else {
        const int p = slot_prefix(b) + (j - 1);  // 0..95
        const size_t prow = ((size_t)head * 96 + p) * 64 + (qrow & 63);
#pragma unroll
        for (int dt = 0; dt < 16; ++dt) {
          ushort4 w;
          w.x = f2bf(o[dt][g][0]); w.y = f2bf(o[dt][g][1]);
          w.z = f2bf(o[dt][g][2]); w.w = f2bf(o[dt][g][3]);
          *reinterpret_cast<ushort4*>(opart + prow * 256 + dt * 16 + lg * 4) = w;
        }
        if (lg == 0) reinterpret_cast<float2*>(mlp)[prow] = float2{mg, lg_};
      }
    }
  }
}

// ----------------------------------------------------- split-KV merge pass
// only rows s >= 1024 (b >= 16, n >= 2 partials): chunk0 in attn/ml0,
// chunks 1..n-1 in opart/mlp at slots prefix(b)+j-1.
__global__ __launch_bounds__(256) void merge(const unsigned short* __restrict__ opart,
                                             const float* __restrict__ ml0,
                                             const float* __restrict__ mlp,
                                             unsigned short* __restrict__ attn) {
  const int wid = threadIdx.x >> 6, lane = threadIdx.x & 63;
  const int task = blockIdx.x * 4 + wid;          // 0..24575 = h*3072 + (s-1024)
  const int h = task / 3072, s = 1024 + task % 3072;
  const int b = s >> 6;
  const int n = (b >> 4) + 1;

  float2 m_l[4];
  m_l[0] = reinterpret_cast<const float2*>(ml0)[h * SEQ + s];
  const int pf = slot_prefix(b);
  size_t prow[4];
  for (int jj = 1; jj < n; ++jj) {
    prow[jj] = ((size_t)h * 96 + pf + jj - 1) * 64 + (s & 63);
    m_l[jj] = reinterpret_cast<const float2*>(mlp)[prow[jj]];
  }

  float M = m_l[0].x;
  for (int jj = 1; jj < n; ++jj) M = fmaxf(M, m_l[jj].x);
  float w[4], L = 0.f;
  for (int jj = 0; jj < n; ++jj) {
    w[jj] = __expf(m_l[jj].x - M);
    L += w[jj] * m_l[jj].y;
  }
  float invL = 1.0f / L;
  for (int jj = 0; jj < n; ++jj) w[jj] *= invL;

  unsigned short* arow = attn + (size_t)s * HID + h * 256;
  ushort4 a = reinterpret_cast<const ushort4*>(arow)[lane];
  float acc0 = w[0] * bf2f(a.x), acc1 = w[0] * bf2f(a.y);
  float acc2 = w[0] * bf2f(a.z), acc3 = w[0] * bf2f(a.w);
  for (int jj = 1; jj < n; ++jj) {
    ushort4 bq = reinterpret_cast<const ushort4*>(opart + prow[jj] * 256)[lane];
    acc0 += w[jj] * bf2f(bq.x); acc1 += w[jj] * bf2f(bq.y);
    acc2 += w[jj] * bf2f(bq.z); acc3 += w[jj] * bf2f(bq.w);
  }
  ushort4 o;
  o.x = f2bf(acc0); o.y = f2bf(acc1); o.z = f2bf(acc2); o.w = f2bf(acc3);
  reinterpret_cast<ushort4*>(arow)[lane] = o;
}

// ---------------------------------------------------------------- launcher
extern "C" void kernel_launch(void* const* d_in, const int* in_sizes, int n_in,
                              void* d_out, int out_size, void* d_ws, size_t ws_size,
                              hipStream_t stream) {
  const float* hs   = (const float*)d_in[0];
  const float* cosb = (const float*)d_in[1];
  const float* sinb = (const float*)d_in[2];
  const float* qkvw = (const float*)d_in[3];
  const float* ow   = (const float*)d_in[4];

  char* ws = (char*)d_ws;
  unsigned short* hs_bf   = (unsigned short*)(ws + 0);           // 16 MB (dead after QKV GEMM)
  unsigned short* wqkv_bf = (unsigned short*)(ws + 16777216);    // 12 MB (dead after QKV GEMM)
  unsigned short* wo_bf   = (unsigned short*)(ws + 29360128);    //  8 MB (live till final GEMM)
  unsigned short* qkv_bf  = (unsigned short*)(ws + 37748736);    // 24 MB (dead after postproc)
  unsigned short* attn_bf = qkv_bf;                              // 16 MB overlay
  unsigned short* q_bf    = (unsigned short*)(ws + 62914560);    // 16 MB
  unsigned short* k_bf    = (unsigned short*)(ws + 79691776);    //  4 MB
  unsigned short* vt_bf   = (unsigned short*)(ws + 83886080);    //  4 MB (staging-ready layout)
  // flash partial overlays (regions dead after the QKV GEMM):
  unsigned short* opart   = (unsigned short*)(ws + 0);           // 8h*96*64*512B = 24 MB
  float*          ml0buf  = (float*)(ws + 25165824);             // 256 KB (32768 float2)
  float*          mlpbuf  = (float*)(ws + 25427968);             // 384 KB (49152 float2)
  int*            ticket  = (int*)(ws + 25821184);               // 8 B (2 sides)

  const int n1 = SEQ * HID / 4, n2 = QKVN * HID / 4, n3 = HID * HID / 4;
  cvt_all<<<dim3((n1 + n2 + n3 + 255) / 256), dim3(256), 0, stream>>>(
      hs, qkvw, ow, hs_bf, n1, n2, n3);

  gemm_bt<true><<<dim3(QKVN / 128, SEQ / 128), dim3(256), 0, stream>>>(
      hs_bf, wqkv_bf, qkv_bf, SEQ, QKVN, HID);

  postproc<<<dim3(SEQ * 12 / 4), dim3(256), 0, stream>>>(qkv_bf, cosb, sinb, q_bf, k_bf, vt_bf);

  hipMemsetAsync(ticket, 0, 8, stream);

  flash<<<dim3(512), dim3(256), 75776, stream>>>(q_bf, k_bf, vt_bf, attn_bf,
                                                 opart, ml0buf, mlpbuf, ticket);

  merge<<<dim3(6144), dim3(256), 0, stream>>>(opart, ml0buf, mlpbuf, attn_bf);

  gemm_bt<false><<<dim3(HID / 128, SEQ / 128), dim3(256), 0, stream>>>(
      attn_bf, wo_bf, d_out, SEQ, HID, HID);
}